// Round 8
// baseline (163.924 us; speedup 1.0000x reference)
//
#include <hip/hip_runtime.h>

typedef __bf16 v8bf __attribute__((ext_vector_type(8)));
typedef float v4f __attribute__((ext_vector_type(4)));
typedef unsigned int v4u __attribute__((ext_vector_type(4)));
typedef unsigned int v2u __attribute__((ext_vector_type(2)));
typedef unsigned short u16;

#define DEVI static __device__ __forceinline__

DEVI float bf2f(u16 u) {
    union { float f; unsigned int i; } c; c.i = ((unsigned int)u) << 16; return c.f;
}
DEVI u16 f2bf(float f) {
    union { __bf16 b; u16 u; } c; c.b = (__bf16)f;   // native HW cvt, RNE
    return c.u;
}

union Frag { v4u u; v8bf v; u16 h[8]; };

#define GLD16(gptr, lptr) __builtin_amdgcn_global_load_lds( \
    (const __attribute__((address_space(1))) void*)(gptr),  \
    (__attribute__((address_space(3))) void*)(lptr), 16, 0, 0)

// raw barrier + counted waits (no __syncthreads: it drains vmcnt(0) and
// kills in-flight prefetch).  "memory" clobber pins ordering.
#define BAR_VM8()  asm volatile("s_waitcnt vmcnt(8)\ns_barrier" ::: "memory")
#define BAR_VM6()  asm volatile("s_waitcnt vmcnt(6)\ns_barrier" ::: "memory")
#define BAR_VM0()  asm volatile("s_waitcnt vmcnt(0)\ns_barrier" ::: "memory")
#define BAR_LGKM() asm volatile("s_waitcnt lgkmcnt(0)\ns_barrier" ::: "memory")

// ---------------------------------------------------------------------------
// fp32 -> bf16 convert (x, Wq, Wk, Wv packed, Wo) + gate precompute (seg 5):
// gates[token*4+g] = 3*sigmoid(x[token,0:12] . Wg[g])
// ---------------------------------------------------------------------------
__global__ __launch_bounds__(256) void convert6(
    const float* __restrict__ x, const float* __restrict__ wq,
    const float* __restrict__ wk, const float* __restrict__ wv,
    const float* __restrict__ wo, const float* __restrict__ Wg,
    u16* __restrict__ xb, u16* __restrict__ wb, u16* __restrict__ wob,
    float* __restrict__ gates)
{
    if (blockIdx.y == 5) {
        const int stride = gridDim.x * 256;
        for (int i = blockIdx.x * 256 + threadIdx.x; i < 4096 * 4; i += stride) {
            const int token = i >> 2, g = i & 3;
            float dot = 0.f;
#pragma unroll
            for (int c = 0; c < 12; c++)
                dot += x[token * 1024 + c] * Wg[g * 12 + c];
            gates[i] = 3.f / (1.f + __expf(-dot));
        }
        return;
    }
    const float* src; u16* dst; int n;
    switch (blockIdx.y) {
        case 0: src = x;  dst = xb;               n = 4096 * 1024; break;
        case 1: src = wq; dst = wb;               n = 1024 * 1024; break;
        case 2: src = wk; dst = wb + 1024 * 1024; n = 256 * 1024;  break;
        case 3: src = wv; dst = wb + 1280 * 1024; n = 256 * 1024;  break;
        default: src = wo; dst = wob;             n = 1024 * 1024; break;
    }
    const int stride = gridDim.x * 256 * 4;
    for (int i = (blockIdx.x * 256 + threadIdx.x) * 4; i < n; i += stride) {
        const float4 f = *(const float4*)(src + i);
        v2u p;
        p[0] = (unsigned int)f2bf(f.x) | ((unsigned int)f2bf(f.y) << 16);
        p[1] = (unsigned int)f2bf(f.z) | ((unsigned int)f2bf(f.w) << 16);
        *(v2u*)(dst + i) = p;
    }
}

// ---------------------------------------------------------------------------
// QKV GEMM: C = A[4096,1024](bf16) * B[1536,1024]^T(bf16), tile 128x128,
// BK=64, DOUBLE-BUFFERED (counted vmcnt(8), never 0 mid-loop).
// 4 waves, each wave 64x64 output = 4x4 16x16 frags.
// Fused epilogue — each wave owns 64 tokens x ONE full 64-d head:
//   Q: RoPE + RMS-norm *1.2 -> qn   K: same -> kn
//   V: acc + gates*ve, written TRANSPOSED straight to vt
// ---------------------------------------------------------------------------
__global__ __launch_bounds__(256) void gemm_qkv(
    const u16* __restrict__ A, const u16* __restrict__ B,
    const float* __restrict__ cs, const float* __restrict__ sn,
    const float* __restrict__ gates, const float* __restrict__ ve,
    u16* __restrict__ qn, u16* __restrict__ kn, u16* __restrict__ vt)
{
    __shared__ __align__(16) u16 As[2][128 * 64];
    __shared__ __align__(16) u16 Bs[2][128 * 64];
    const int tid  = threadIdx.x;
    const int lane = tid & 63, l15 = lane & 15, quad = (lane >> 4) & 3;
    const int w    = tid >> 6;
    const int wr   = (w >> 1) * 64, wc = (w & 1) * 64;
    const int m0   = blockIdx.x * 128, n0 = blockIdx.y * 128;

    const int r0 = tid >> 3;         // 0..31
    const int c0 = (tid & 7) * 8;    // 0..56
    const u16* ag = A + m0 * 1024 + r0 * 1024 + c0;
    const u16* bg = B + n0 * 1024 + r0 * 1024 + c0;
    const int lo = r0 * 64 + c0;

    v4f acc[4][4];
    const v4f vzero = {0.f, 0.f, 0.f, 0.f};
#pragma unroll
    for (int i = 0; i < 4; i++)
#pragma unroll
        for (int j = 0; j < 4; j++) acc[i][j] = vzero;

#define QKV_STAGE(k0, buf) {                                        \
        const u16* a_ = ag + (k0);  const u16* b_ = bg + (k0);      \
        u16* al_ = &As[buf][lo];    u16* bl_ = &Bs[buf][lo];        \
        GLD16(a_,             al_);                                 \
        GLD16(a_ + 32 * 1024, al_ + 32 * 64);                       \
        GLD16(a_ + 64 * 1024, al_ + 64 * 64);                       \
        GLD16(a_ + 96 * 1024, al_ + 96 * 64);                       \
        GLD16(b_,             bl_);                                 \
        GLD16(b_ + 32 * 1024, bl_ + 32 * 64);                       \
        GLD16(b_ + 64 * 1024, bl_ + 64 * 64);                       \
        GLD16(b_ + 96 * 1024, bl_ + 96 * 64);                       \
    }

    QKV_STAGE(0, 0);
    for (int t = 0; t < 16; ++t) {
        if (t < 15) {
            QKV_STAGE((t + 1) * 64, (t + 1) & 1);
            BAR_VM8();              // tile t's 8 loads landed; t+1 in flight
        } else {
            BAR_VM0();
        }
        const u16* Asb = As[t & 1];
        const u16* Bsb = Bs[t & 1];
#pragma unroll
        for (int ks = 0; ks < 2; ks++) {
            v8bf af[4], bv[4];
#pragma unroll
            for (int mi = 0; mi < 4; mi++)
                af[mi] = *(const v8bf*)&Asb[(wr + mi * 16 + l15) * 64 + ks * 32 + quad * 8];
#pragma unroll
            for (int ni = 0; ni < 4; ni++)
                bv[ni] = *(const v8bf*)&Bsb[(wc + ni * 16 + l15) * 64 + ks * 32 + quad * 8];
#pragma unroll
            for (int ni = 0; ni < 4; ni++)
#pragma unroll
                for (int mi = 0; mi < 4; mi++)
                    acc[mi][ni] = __builtin_amdgcn_mfma_f32_16x16x32_bf16(af[mi], bv[ni], acc[mi][ni], 0, 0, 0);
        }
        BAR_LGKM();                 // all reads of buf[t&1] retired
    }
#undef QKV_STAGE

    // ---- fused QKV epilogue ----
    const int hcol = n0 + wc;          // start col of this wave's head
    if (hcol < 1280) {                 // Q or K head: RoPE + RMS-norm
        const bool isQ = (hcol < 1024);
        u16* dst = isQ ? (qn + (hcol >> 6) * 64) : (kn + ((hcol - 1024) >> 6) * 64);
        const int dstride = isQ ? 1024 : 256;
#pragma unroll
        for (int mi = 0; mi < 4; mi++) {
#pragma unroll
            for (int r = 0; r < 4; r++) {
                const int row = m0 + wr + mi * 16 + quad * 4 + r;
                const int pos = row & 1023;
                const float c0_ = cs[pos * 32 + l15],      s0_ = sn[pos * 32 + l15];
                const float c1_ = cs[pos * 32 + 16 + l15], s1_ = sn[pos * 32 + 16 + l15];
                const float y0 = acc[mi][0][r] * c0_ + acc[mi][2][r] * s0_;
                const float y2 = acc[mi][2][r] * c0_ - acc[mi][0][r] * s0_;
                const float y1 = acc[mi][1][r] * c1_ + acc[mi][3][r] * s1_;
                const float y3 = acc[mi][3][r] * c1_ - acc[mi][1][r] * s1_;
                float ss = y0 * y0 + y1 * y1 + y2 * y2 + y3 * y3;
#pragma unroll
                for (int off = 8; off >= 1; off >>= 1)
                    ss += __shfl_xor(ss, off, 64);
                const float inv = rsqrtf(ss * (1.0f / 64.0f) + 1.1920929e-7f) * 1.2f;
                u16* d = dst + row * dstride;
                d[l15]      = f2bf(y0 * inv);
                d[16 + l15] = f2bf(y1 * inv);
                d[32 + l15] = f2bf(y2 * inv);
                d[48 + l15] = f2bf(y3 * inv);
            }
        }
    } else {                           // V head: + gate * ve, transposed store
        const int g = (hcol - 1280) >> 6;
#pragma unroll
        for (int mi = 0; mi < 4; mi++) {
            const int row0 = m0 + wr + mi * 16 + quad * 4;   // rows row0..row0+3
            const int b_ = row0 >> 10, t_ = row0 & 1023;     // same b for all 4 r
            float gate[4];
#pragma unroll
            for (int r = 0; r < 4; r++) gate[r] = gates[(row0 + r) * 4 + g];
#pragma unroll
            for (int ni = 0; ni < 4; ni++) {
                const int d = ni * 16 + l15;
                union { u16 h[4]; v2u u; } pk;
#pragma unroll
                for (int r = 0; r < 4; r++)
                    pk.h[r] = f2bf(acc[mi][ni][r] + gate[r] * ve[(row0 + r) * 256 + g * 64 + d]);
                // t_ is a multiple of 4 -> 8B-aligned store
                *(v2u*)&vt[((b_ * 4 + g) * 64 + d) * 1024 + t_] = pk.u;
            }
        }
    }
}

// ---------------------------------------------------------------------------
// Output projection GEMM: C = A[4096,1024](bf16) * B[1024,1024]^T(bf16),
// tile 64x128 BK=64, double-buffered, counted vmcnt(6).  512 blocks ->
// 2 blocks/CU, 8 waves/CU (r4 config: occupancy > frag-read balance here;
// r6's 128^2 @ 1/CU was -3us).  Plain fp32 store.
// ---------------------------------------------------------------------------
__global__ __launch_bounds__(256) void gemm_out(
    const u16* __restrict__ A, const u16* __restrict__ B,
    float* __restrict__ C, int N)
{
    __shared__ __align__(16) u16 As[2][64 * 64];
    __shared__ __align__(16) u16 Bs[2][128 * 64];
    const int tid  = threadIdx.x;
    const int lane = tid & 63, l15 = lane & 15, quad = (lane >> 4) & 3;
    const int w    = tid >> 6;
    const int wr   = (w >> 1) * 32, wc = (w & 1) * 64;
    const int m0   = blockIdx.x * 64, n0 = blockIdx.y * 128;

    const int r0 = tid >> 3;
    const int c0 = (tid & 7) * 8;
    const u16* ag = A + m0 * 1024 + r0 * 1024 + c0;
    const u16* bg = B + n0 * 1024 + r0 * 1024 + c0;
    const int lo = r0 * 64 + c0;

    v4f acc[2][4];
    const v4f vzero = {0.f, 0.f, 0.f, 0.f};
#pragma unroll
    for (int i = 0; i < 2; i++)
#pragma unroll
        for (int j = 0; j < 4; j++) acc[i][j] = vzero;

#define OUT_STAGE(k0, buf) {                                        \
        const u16* a_ = ag + (k0);  const u16* b_ = bg + (k0);      \
        u16* al_ = &As[buf][lo];    u16* bl_ = &Bs[buf][lo];        \
        GLD16(a_,             al_);                                 \
        GLD16(a_ + 32 * 1024, al_ + 32 * 64);                       \
        GLD16(b_,             bl_);                                 \
        GLD16(b_ + 32 * 1024, bl_ + 32 * 64);                       \
        GLD16(b_ + 64 * 1024, bl_ + 64 * 64);                       \
        GLD16(b_ + 96 * 1024, bl_ + 96 * 64);                       \
    }

    OUT_STAGE(0, 0);
    for (int t = 0; t < 16; ++t) {
        if (t < 15) {
            OUT_STAGE((t + 1) * 64, (t + 1) & 1);
            BAR_VM6();
        } else {
            BAR_VM0();
        }
        const u16* Asb = As[t & 1];
        const u16* Bsb = Bs[t & 1];
#pragma unroll
        for (int ks = 0; ks < 2; ks++) {
            v8bf af[2];
#pragma unroll
            for (int mi = 0; mi < 2; mi++)
                af[mi] = *(const v8bf*)&Asb[(wr + mi * 16 + l15) * 64 + ks * 32 + quad * 8];
#pragma unroll
            for (int ni = 0; ni < 4; ni++) {
                v8bf bv = *(const v8bf*)&Bsb[(wc + ni * 16 + l15) * 64 + ks * 32 + quad * 8];
#pragma unroll
                for (int mi = 0; mi < 2; mi++)
                    acc[mi][ni] = __builtin_amdgcn_mfma_f32_16x16x32_bf16(af[mi], bv, acc[mi][ni], 0, 0, 0);
            }
        }
        BAR_LGKM();
    }
#undef OUT_STAGE

#pragma unroll
    for (int mi = 0; mi < 2; mi++) {
        const int row = m0 + wr + mi * 16 + quad * 4;
#pragma unroll
        for (int ni = 0; ni < 4; ni++) {
            const int col = n0 + wc + ni * 16 + l15;
#pragma unroll
            for (int r = 0; r < 4; r++)
                C[(row + r) * N + col] = acc[mi][ni][r];
        }
    }
}

// ---------------------------------------------------------------------------
// Sliding-window flash attention v9:
//  - V is NOT staged in LDS: PV B-fragments load direct from vt (L2-resident,
//    ~40 KB working set/block; staging was overhead — guide lesson #7).
//  - K double-buffered in LDS -> ONE barrier per K-tile (passing barrier t
//    implies all waves finished iteration t-1's reads of the buffer being
//    overwritten).  Ps is wave-private (same-wave lgkm ordering, no barrier).
//  - LDS 27 KB -> 4 blocks/CU co-resident (grid 1024), 16 waves/CU.
// Fixed-max softmax with base-2 exp: Q pre-scaled by 0.125*log2(e);
// p = exp2(a - 12*log2e) is a single v_exp_f32.
// ---------------------------------------------------------------------------
__global__ __launch_bounds__(256) void attn(
    const u16* __restrict__ qn, const u16* __restrict__ kn,
    const u16* __restrict__ vt, u16* __restrict__ yo)
{
    __shared__ __align__(16) u16 Ks[2][64 * 72];
    __shared__ __align__(16) u16 Ps[4][16 * 72];
    const int tid  = threadIdx.x;
    const int w    = tid >> 6, lane = tid & 63, l15 = lane & 15, quad = (lane >> 4) & 3;
    const int qb   = blockIdx.x, h = blockIdx.y, b = blockIdx.z;
    const int g    = h >> 2;
    const int qbase = qb * 64;
    const int qabs0 = qbase + w * 16;     // this wave's 16 q-rows
    const int tok0  = b * 1024 + qabs0;
    u16* pw = Ps[w];

    v8bf qf[2];
#pragma unroll
    for (int ks = 0; ks < 2; ks++) {
        Frag f;
        f.u = *(const v4u*)&qn[(tok0 + l15) * 1024 + h * 64 + ks * 32 + quad * 8];
#pragma unroll
        for (int j = 0; j < 8; j++) f.h[j] = f2bf(0.18033688f * bf2f(f.h[j]));  // 0.125*log2e
        qf[ks] = f.v;
    }

    v4f o[4];
    float li[4];
    const v4f vzero = {0.f, 0.f, 0.f, 0.f};
#pragma unroll
    for (int nd = 0; nd < 4; nd++) o[nd] = vzero;
#pragma unroll
    for (int r = 0; r < 4; r++) li[r] = 0.f;

    const int row = tid >> 2, ch = (tid & 3) * 16;
    const int kstart = (qbase >= 256) ? qbase - 256 : 0;
    const int kend   = qbase;          // tile [kend, kend+63] covers q-row qbase+63
    const u16* vrow0 = vt + ((b * 4 + g) * 64) * 1024;   // V^T base for this group

    // K prefetch registers (named, compile-time indexed — rule #20)
    v4u ka, kb;
#define LOADK(kb_)  {                                                         \
        const int goff_ = (b * 1024 + (kb_) + row) * 256 + g * 64 + ch;       \
        ka = *(const v4u*)&kn[goff_];                                         \
        kb = *(const v4u*)&kn[goff_ + 8];                                     \
    }

    // prologue: stage tile 0 into Ks[0]
    LOADK(kstart);
    *(v4u*)&Ks[0][row * 72 + ch]     = ka;   // compiler inserts vmcnt wait
    *(v4u*)&Ks[0][row * 72 + ch + 8] = kb;

    int t = 0;
    for (int kbase = kstart; kbase <= kend; kbase += 64, ++t) {
        const int cur = t & 1;
        const bool more = (kbase + 64 <= kend);
        if (more) LOADK(kbase + 64);          // async prefetch (uniform branch)
        BAR_LGKM();                           // Ks[cur] writes visible to all

        bool skip2[4], full2[4];
#pragma unroll
        for (int ni = 0; ni < 4; ni++) {
            const int left = kbase + ni * 16;
            skip2[ni] = (left > qabs0 + 15) || (qabs0 - (left + 15) > 256);
            full2[ni] = ((left + 15) <= qabs0) && ((qabs0 + 15 - left) <= 256);
        }

        const u16* Kc = Ks[cur];
#pragma unroll
        for (int ni = 0; ni < 4; ni++) {
            if (skip2[ni]) {
#pragma unroll
                for (int r = 0; r < 4; r++)
                    pw[(quad * 4 + r) * 72 + ni * 16 + l15] = 0;
                continue;
            }
            v8bf kf0 = *(const v8bf*)&Kc[(ni * 16 + l15) * 72 + quad * 8];
            v8bf kf1 = *(const v8bf*)&Kc[(ni * 16 + l15) * 72 + 32 + quad * 8];
            v4f a = vzero;
            a = __builtin_amdgcn_mfma_f32_16x16x32_bf16(qf[0], kf0, a, 0, 0, 0);
            a = __builtin_amdgcn_mfma_f32_16x16x32_bf16(qf[1], kf1, a, 0, 0, 0);
            if (!full2[ni]) {
                const int kj = kbase + ni * 16 + l15;
#pragma unroll
                for (int r = 0; r < 4; r++) {
                    const int qi = qabs0 + quad * 4 + r;
                    if (!((kj <= qi) && (qi - kj <= 256))) a[r] = -1e30f;
                }
            }
#pragma unroll
            for (int r = 0; r < 4; r++) {
                const float p = exp2f(a[r] - 17.312340f);   // 12*log2e
                li[r] += p;
                pw[(quad * 4 + r) * 72 + ni * 16 + l15] = f2bf(p);
            }
        }

        // PV: P from wave-private LDS, V fragments DIRECT from global (L2)
#pragma unroll
        for (int ks = 0; ks < 2; ks++) {
            if (skip2[2 * ks] && skip2[2 * ks + 1]) continue;
            v8bf af = *(const v8bf*)&pw[l15 * 72 + ks * 32 + quad * 8];
            const u16* vb_ = vrow0 + kbase + ks * 32 + quad * 8;
#pragma unroll
            for (int nd = 0; nd < 4; nd++) {
                v8bf bv = *(const v8bf*)&vb_[(nd * 16 + l15) * 1024];
                o[nd] = __builtin_amdgcn_mfma_f32_16x16x32_bf16(af, bv, o[nd], 0, 0, 0);
            }
        }

        if (more) {   // write next K tile into the other buffer (no barrier:
                      // all waves passed BAR -> finished t-1's reads of it)
            u16* kd = &Ks[cur ^ 1][row * 72 + ch];
            *(v4u*)kd       = ka;
            *(v4u*)(kd + 8) = kb;
        }
    }
#undef LOADK

#pragma unroll
    for (int off = 8; off >= 1; off >>= 1)
#pragma unroll
        for (int r = 0; r < 4; r++)
            li[r] += __shfl_xor(li[r], off, 64);
    float inv[4];
#pragma unroll
    for (int r = 0; r < 4; r++) inv[r] = 1.f / li[r];
#pragma unroll
    for (int nd = 0; nd < 4; nd++) {
        const int col = h * 64 + nd * 16 + l15;
#pragma unroll
        for (int r = 0; r < 4; r++) {
            const int row2 = tok0 + quad * 4 + r;
            yo[row2 * 1024 + col] = f2bf(o[nd][r] * inv[r]);
        }
    }
}

// ---------------------------------------------------------------------------
extern "C" void kernel_launch(void* const* d_in, const int* in_sizes, int n_in,
                              void* d_out, int out_size, void* d_ws, size_t ws_size,
                              hipStream_t stream)
{
    const float* x  = (const float*)d_in[0];
    const float* ve = (const float*)d_in[1];
    const float* cs = (const float*)d_in[2];
    const float* sn = (const float*)d_in[3];
    const float* Wq = (const float*)d_in[4];
    const float* Wk = (const float*)d_in[5];
    const float* Wv = (const float*)d_in[6];
    const float* Wo = (const float*)d_in[7];
    const float* Wg = (const float*)d_in[8];
    // d_in[9] = window_size (fixed 256, hard-coded)

    u16*   xb    = (u16*)d_ws;                 // 4096 x 1024
    u16*   wb    = xb  + 4096 * 1024;          // 1536 x 1024  [Wq;Wk;Wv]
    u16*   wob   = wb  + 1536 * 1024;          // 1024 x 1024  Wo
    u16*   qn    = wob + 1024 * 1024;          // 4096 x 1024
    u16*   kn    = qn  + 4096 * 1024;          // 4096 x 256
    u16*   vt    = kn  + 4096 * 256;           // [4][4][64][1024] transposed V
    u16*   ay    = vt  + 4096 * 256;           // 4096 x 1024 attention out
    float* gates = (float*)(ay + 4096 * 1024); // 4096 x 4

    convert6<<<dim3(512, 6), 256, 0, stream>>>(x, Wq, Wk, Wv, Wo, Wg, xb, wb, wob, gates);
    gemm_qkv<<<dim3(32, 12), 256, 0, stream>>>(xb, wb, cs, sn, gates, ve, qn, kn, vt);
    attn<<<dim3(16, 16, 4), 256, 0, stream>>>(qn, kn, vt, ay);
    gemm_out<<<dim3(64, 8), 256, 0, stream>>>(ay, wob, (float*)d_out, 1024);
}

// Round 9
// 150.463 us; speedup vs baseline: 1.0895x; 1.0895x over previous
//
#include <hip/hip_runtime.h>

typedef __bf16 v8bf __attribute__((ext_vector_type(8)));
typedef float v4f __attribute__((ext_vector_type(4)));
typedef unsigned int v4u __attribute__((ext_vector_type(4)));
typedef unsigned int v2u __attribute__((ext_vector_type(2)));
typedef unsigned short u16;

#define DEVI static __device__ __forceinline__

DEVI float bf2f(u16 u) {
    union { float f; unsigned int i; } c; c.i = ((unsigned int)u) << 16; return c.f;
}
DEVI u16 f2bf(float f) {
    union { __bf16 b; u16 u; } c; c.b = (__bf16)f;   // native HW cvt, RNE
    return c.u;
}

union Frag { v4u u; v8bf v; u16 h[8]; };

#define GLD16(gptr, lptr) __builtin_amdgcn_global_load_lds( \
    (const __attribute__((address_space(1))) void*)(gptr),  \
    (__attribute__((address_space(3))) void*)(lptr), 16, 0, 0)

// raw barrier + counted waits (no __syncthreads: it drains vmcnt(0) and
// kills in-flight prefetch).  "memory" clobber pins ordering.
#define BAR_VM6()  asm volatile("s_waitcnt vmcnt(6)\ns_barrier" ::: "memory")
#define BAR_VM0()  asm volatile("s_waitcnt vmcnt(0)\ns_barrier" ::: "memory")
#define BAR_LGKM() asm volatile("s_waitcnt lgkmcnt(0)\ns_barrier" ::: "memory")

// ---------------------------------------------------------------------------
// fp32 -> bf16 convert (x, Wq, Wk, Wv packed, Wo) + gate precompute (seg 5):
// gates[token*4+g] = 3*sigmoid(x[token,0:12] . Wg[g])
// ---------------------------------------------------------------------------
__global__ __launch_bounds__(256) void convert6(
    const float* __restrict__ x, const float* __restrict__ wq,
    const float* __restrict__ wk, const float* __restrict__ wv,
    const float* __restrict__ wo, const float* __restrict__ Wg,
    u16* __restrict__ xb, u16* __restrict__ wb, u16* __restrict__ wob,
    float* __restrict__ gates)
{
    if (blockIdx.y == 5) {
        const int stride = gridDim.x * 256;
        for (int i = blockIdx.x * 256 + threadIdx.x; i < 4096 * 4; i += stride) {
            const int token = i >> 2, g = i & 3;
            float dot = 0.f;
#pragma unroll
            for (int c = 0; c < 12; c++)
                dot += x[token * 1024 + c] * Wg[g * 12 + c];
            gates[i] = 3.f / (1.f + __expf(-dot));
        }
        return;
    }
    const float* src; u16* dst; int n;
    switch (blockIdx.y) {
        case 0: src = x;  dst = xb;               n = 4096 * 1024; break;
        case 1: src = wq; dst = wb;               n = 1024 * 1024; break;
        case 2: src = wk; dst = wb + 1024 * 1024; n = 256 * 1024;  break;
        case 3: src = wv; dst = wb + 1280 * 1024; n = 256 * 1024;  break;
        default: src = wo; dst = wob;             n = 1024 * 1024; break;
    }
    const int stride = gridDim.x * 256 * 4;
    for (int i = (blockIdx.x * 256 + threadIdx.x) * 4; i < n; i += stride) {
        const float4 f = *(const float4*)(src + i);
        v2u p;
        p[0] = (unsigned int)f2bf(f.x) | ((unsigned int)f2bf(f.y) << 16);
        p[1] = (unsigned int)f2bf(f.z) | ((unsigned int)f2bf(f.w) << 16);
        *(v2u*)(dst + i) = p;
    }
}

// ---------------------------------------------------------------------------
// QKV GEMM v2: tile 64x128 (was 128x128).  r8 counters showed 128^2 @ 384
// blocks = 1.5 blocks/CU, MfmaUtil 10.5%, Occupancy 14.6% -> latency-bound
// with a half-empty dispatch tail.  64x128 -> grid (64,12) = 768 blocks =
// exactly 3 blocks/CU (48 KB LDS x3 = 144 <= 160), 3 waves/SIMD, no tail.
// BK=64 double-buffered, counted vmcnt(6).  4 waves, each 32x64 output
// (2x4 frags).  Fused epilogue — wave owns 32 tokens x ONE full 64-d head:
//   Q: RoPE + RMS-norm *1.2 -> qn   K: same -> kn
//   V: acc + gates*ve, written TRANSPOSED straight to vt
// ---------------------------------------------------------------------------
__global__ __launch_bounds__(256) void gemm_qkv(
    const u16* __restrict__ A, const u16* __restrict__ B,
    const float* __restrict__ cs, const float* __restrict__ sn,
    const float* __restrict__ gates, const float* __restrict__ ve,
    u16* __restrict__ qn, u16* __restrict__ kn, u16* __restrict__ vt)
{
    __shared__ __align__(16) u16 As[2][64 * 64];
    __shared__ __align__(16) u16 Bs[2][128 * 64];
    const int tid  = threadIdx.x;
    const int lane = tid & 63, l15 = lane & 15, quad = (lane >> 4) & 3;
    const int w    = tid >> 6;
    const int wr   = (w >> 1) * 32, wc = (w & 1) * 64;
    const int m0   = blockIdx.x * 64, n0 = blockIdx.y * 128;

    const int r0 = tid >> 3;         // 0..31
    const int c0 = (tid & 7) * 8;    // 0..56
    const u16* ag = A + m0 * 1024 + r0 * 1024 + c0;
    const u16* bg = B + n0 * 1024 + r0 * 1024 + c0;
    const int lo = r0 * 64 + c0;

    v4f acc[2][4];
    const v4f vzero = {0.f, 0.f, 0.f, 0.f};
#pragma unroll
    for (int i = 0; i < 2; i++)
#pragma unroll
        for (int j = 0; j < 4; j++) acc[i][j] = vzero;

#define QKV_STAGE(k0, buf) {                                        \
        const u16* a_ = ag + (k0);  const u16* b_ = bg + (k0);      \
        u16* al_ = &As[buf][lo];    u16* bl_ = &Bs[buf][lo];        \
        GLD16(a_,             al_);                                 \
        GLD16(a_ + 32 * 1024, al_ + 32 * 64);                       \
        GLD16(b_,             bl_);                                 \
        GLD16(b_ + 32 * 1024, bl_ + 32 * 64);                       \
        GLD16(b_ + 64 * 1024, bl_ + 64 * 64);                       \
        GLD16(b_ + 96 * 1024, bl_ + 96 * 64);                       \
    }

    QKV_STAGE(0, 0);
    for (int t = 0; t < 16; ++t) {
        if (t < 15) {
            QKV_STAGE((t + 1) * 64, (t + 1) & 1);
            BAR_VM6();              // tile t's 6 loads landed; t+1 in flight
        } else {
            BAR_VM0();
        }
        const u16* Asb = As[t & 1];
        const u16* Bsb = Bs[t & 1];
#pragma unroll
        for (int ks = 0; ks < 2; ks++) {
            v8bf af[2];
#pragma unroll
            for (int mi = 0; mi < 2; mi++)
                af[mi] = *(const v8bf*)&Asb[(wr + mi * 16 + l15) * 64 + ks * 32 + quad * 8];
#pragma unroll
            for (int ni = 0; ni < 4; ni++) {
                v8bf bv = *(const v8bf*)&Bsb[(wc + ni * 16 + l15) * 64 + ks * 32 + quad * 8];
#pragma unroll
                for (int mi = 0; mi < 2; mi++)
                    acc[mi][ni] = __builtin_amdgcn_mfma_f32_16x16x32_bf16(af[mi], bv, acc[mi][ni], 0, 0, 0);
            }
        }
        BAR_LGKM();                 // all reads of buf[t&1] retired
    }
#undef QKV_STAGE

    // ---- fused QKV epilogue ----
    const int hcol = n0 + wc;          // start col of this wave's head
    if (hcol < 1280) {                 // Q or K head: RoPE + RMS-norm
        const bool isQ = (hcol < 1024);
        u16* dst = isQ ? (qn + (hcol >> 6) * 64) : (kn + ((hcol - 1024) >> 6) * 64);
        const int dstride = isQ ? 1024 : 256;
#pragma unroll
        for (int mi = 0; mi < 2; mi++) {
#pragma unroll
            for (int r = 0; r < 4; r++) {
                const int row = m0 + wr + mi * 16 + quad * 4 + r;
                const int pos = row & 1023;
                const float c0_ = cs[pos * 32 + l15],      s0_ = sn[pos * 32 + l15];
                const float c1_ = cs[pos * 32 + 16 + l15], s1_ = sn[pos * 32 + 16 + l15];
                const float y0 = acc[mi][0][r] * c0_ + acc[mi][2][r] * s0_;
                const float y2 = acc[mi][2][r] * c0_ - acc[mi][0][r] * s0_;
                const float y1 = acc[mi][1][r] * c1_ + acc[mi][3][r] * s1_;
                const float y3 = acc[mi][3][r] * c1_ - acc[mi][1][r] * s1_;
                float ss = y0 * y0 + y1 * y1 + y2 * y2 + y3 * y3;
#pragma unroll
                for (int off = 8; off >= 1; off >>= 1)
                    ss += __shfl_xor(ss, off, 64);
                const float inv = rsqrtf(ss * (1.0f / 64.0f) + 1.1920929e-7f) * 1.2f;
                u16* d = dst + row * dstride;
                d[l15]      = f2bf(y0 * inv);
                d[16 + l15] = f2bf(y1 * inv);
                d[32 + l15] = f2bf(y2 * inv);
                d[48 + l15] = f2bf(y3 * inv);
            }
        }
    } else {                           // V head: + gate * ve, transposed store
        const int g = (hcol - 1280) >> 6;
#pragma unroll
        for (int mi = 0; mi < 2; mi++) {
            const int row0 = m0 + wr + mi * 16 + quad * 4;   // rows row0..row0+3
            const int b_ = row0 >> 10, t_ = row0 & 1023;     // same b for all 4 r
            float gate[4];
#pragma unroll
            for (int r = 0; r < 4; r++) gate[r] = gates[(row0 + r) * 4 + g];
#pragma unroll
            for (int ni = 0; ni < 4; ni++) {
                const int d = ni * 16 + l15;
                union { u16 h[4]; v2u u; } pk;
#pragma unroll
                for (int r = 0; r < 4; r++)
                    pk.h[r] = f2bf(acc[mi][ni][r] + gate[r] * ve[(row0 + r) * 256 + g * 64 + d]);
                // t_ is a multiple of 4 -> 8B-aligned store
                *(v2u*)&vt[((b_ * 4 + g) * 64 + d) * 1024 + t_] = pk.u;
            }
        }
    }
}

// ---------------------------------------------------------------------------
// Output projection GEMM: C = A[4096,1024](bf16) * B[1024,1024]^T(bf16),
// tile 64x128 BK=64, double-buffered, counted vmcnt(6).  512 blocks ->
// 2 blocks/CU, 8 waves/CU (r4 config, A/B-proven vs 128^2 @ 1/CU).
// Plain fp32 store.
// ---------------------------------------------------------------------------
__global__ __launch_bounds__(256) void gemm_out(
    const u16* __restrict__ A, const u16* __restrict__ B,
    float* __restrict__ C, int N)
{
    __shared__ __align__(16) u16 As[2][64 * 64];
    __shared__ __align__(16) u16 Bs[2][128 * 64];
    const int tid  = threadIdx.x;
    const int lane = tid & 63, l15 = lane & 15, quad = (lane >> 4) & 3;
    const int w    = tid >> 6;
    const int wr   = (w >> 1) * 32, wc = (w & 1) * 64;
    const int m0   = blockIdx.x * 64, n0 = blockIdx.y * 128;

    const int r0 = tid >> 3;
    const int c0 = (tid & 7) * 8;
    const u16* ag = A + m0 * 1024 + r0 * 1024 + c0;
    const u16* bg = B + n0 * 1024 + r0 * 1024 + c0;
    const int lo = r0 * 64 + c0;

    v4f acc[2][4];
    const v4f vzero = {0.f, 0.f, 0.f, 0.f};
#pragma unroll
    for (int i = 0; i < 2; i++)
#pragma unroll
        for (int j = 0; j < 4; j++) acc[i][j] = vzero;

#define OUT_STAGE(k0, buf) {                                        \
        const u16* a_ = ag + (k0);  const u16* b_ = bg + (k0);      \
        u16* al_ = &As[buf][lo];    u16* bl_ = &Bs[buf][lo];        \
        GLD16(a_,             al_);                                 \
        GLD16(a_ + 32 * 1024, al_ + 32 * 64);                       \
        GLD16(b_,             bl_);                                 \
        GLD16(b_ + 32 * 1024, bl_ + 32 * 64);                       \
        GLD16(b_ + 64 * 1024, bl_ + 64 * 64);                       \
        GLD16(b_ + 96 * 1024, bl_ + 96 * 64);                       \
    }

    OUT_STAGE(0, 0);
    for (int t = 0; t < 16; ++t) {
        if (t < 15) {
            OUT_STAGE((t + 1) * 64, (t + 1) & 1);
            BAR_VM6();
        } else {
            BAR_VM0();
        }
        const u16* Asb = As[t & 1];
        const u16* Bsb = Bs[t & 1];
#pragma unroll
        for (int ks = 0; ks < 2; ks++) {
            v8bf af[2];
#pragma unroll
            for (int mi = 0; mi < 2; mi++)
                af[mi] = *(const v8bf*)&Asb[(wr + mi * 16 + l15) * 64 + ks * 32 + quad * 8];
#pragma unroll
            for (int ni = 0; ni < 4; ni++) {
                v8bf bv = *(const v8bf*)&Bsb[(wc + ni * 16 + l15) * 64 + ks * 32 + quad * 8];
#pragma unroll
                for (int mi = 0; mi < 2; mi++)
                    acc[mi][ni] = __builtin_amdgcn_mfma_f32_16x16x32_bf16(af[mi], bv, acc[mi][ni], 0, 0, 0);
            }
        }
        BAR_LGKM();
    }
#undef OUT_STAGE

#pragma unroll
    for (int mi = 0; mi < 2; mi++) {
        const int row = m0 + wr + mi * 16 + quad * 4;
#pragma unroll
        for (int ni = 0; ni < 4; ni++) {
            const int col = n0 + wc + ni * 16 + l15;
#pragma unroll
            for (int r = 0; r < 4; r++)
                C[(row + r) * N + col] = acc[mi][ni][r];
        }
    }
}

// ---------------------------------------------------------------------------
// Sliding-window flash attention v8 (r4 known-good, REVERT of v9 which
// regressed +7us: direct-L2 V fragment loads in the MFMA critical path cost
// more than LDS staging).  QBLK=64 + T14 async-stage split; K/V tile t+1
// prefetched into registers before compute(t); ds_write lands after the
// post-compute barrier.  Single-buffered LDS (25 KB) -> 4 blocks/CU.
// Fixed-max softmax with base-2 exp: Q pre-scaled by 0.125*log2(e);
// p = exp2(a - 12*log2e) is a single v_exp_f32.
// ---------------------------------------------------------------------------
__global__ __launch_bounds__(256) void attn(
    const u16* __restrict__ qn, const u16* __restrict__ kn,
    const u16* __restrict__ vt, u16* __restrict__ yo)
{
    __shared__ __align__(16) u16 Ks[64 * 72];
    __shared__ __align__(16) u16 VTs[64 * 72];
    __shared__ __align__(16) u16 Ps[4][16 * 72];
    const int tid  = threadIdx.x;
    const int w    = tid >> 6, lane = tid & 63, l15 = lane & 15, quad = (lane >> 4) & 3;
    const int qb   = blockIdx.x, h = blockIdx.y, b = blockIdx.z;
    const int g    = h >> 2;
    const int qbase = qb * 64;
    const int qabs0 = qbase + w * 16;     // this wave's 16 q-rows
    const int tok0  = b * 1024 + qabs0;
    u16* pw = Ps[w];

    v8bf qf[2];
#pragma unroll
    for (int ks = 0; ks < 2; ks++) {
        Frag f;
        f.u = *(const v4u*)&qn[(tok0 + l15) * 1024 + h * 64 + ks * 32 + quad * 8];
#pragma unroll
        for (int j = 0; j < 8; j++) f.h[j] = f2bf(0.18033688f * bf2f(f.h[j]));  // 0.125*log2e
        qf[ks] = f.v;
    }

    v4f o[4];
    float li[4];
    const v4f vzero = {0.f, 0.f, 0.f, 0.f};
#pragma unroll
    for (int nd = 0; nd < 4; nd++) o[nd] = vzero;
#pragma unroll
    for (int r = 0; r < 4; r++) li[r] = 0.f;

    const int row = tid >> 2, ch = (tid & 3) * 16;
    const int kstart = (qbase >= 256) ? qbase - 256 : 0;
    const int kend   = qbase;          // tile [kend, kend+63] covers q-row qbase+63

    // prefetch registers (named, compile-time indexed — rule #20)
    v4u ka, kb, va, vb;
#define LOADKV(kb_)  {                                                        \
        const int goff_ = (b * 1024 + (kb_) + row) * 256 + g * 64 + ch;       \
        ka = *(const v4u*)&kn[goff_];                                         \
        kb = *(const v4u*)&kn[goff_ + 8];                                     \
        const u16* vs_ = vt + ((b * 4 + g) * 64 + row) * 1024 + (kb_) + ch;   \
        va = *(const v4u*)vs_;                                                \
        vb = *(const v4u*)(vs_ + 8);                                          \
    }

    LOADKV(kstart);
    for (int kbase = kstart; kbase <= kend; kbase += 64) {
        // write current tile (compiler inserts the vmcnt wait on ka..vb)
        *(v4u*)&Ks[row * 72 + ch]      = ka;
        *(v4u*)&Ks[row * 72 + ch + 8]  = kb;
        *(v4u*)&VTs[row * 72 + ch]     = va;
        *(v4u*)&VTs[row * 72 + ch + 8] = vb;
        if (kbase + 64 <= kend) LOADKV(kbase + 64);   // prefetch next (uniform branch)
        BAR_LGKM();                                    // LDS writes visible

        bool skip2[4], full2[4];
#pragma unroll
        for (int ni = 0; ni < 4; ni++) {
            const int left = kbase + ni * 16;
            skip2[ni] = (left > qabs0 + 15) || (qabs0 - (left + 15) > 256);
            full2[ni] = ((left + 15) <= qabs0) && ((qabs0 + 15 - left) <= 256);
        }

#pragma unroll
        for (int ni = 0; ni < 4; ni++) {
            if (skip2[ni]) {
#pragma unroll
                for (int r = 0; r < 4; r++)
                    pw[(quad * 4 + r) * 72 + ni * 16 + l15] = 0;
                continue;
            }
            v8bf kf0 = *(const v8bf*)&Ks[(ni * 16 + l15) * 72 + quad * 8];
            v8bf kf1 = *(const v8bf*)&Ks[(ni * 16 + l15) * 72 + 32 + quad * 8];
            v4f a = vzero;
            a = __builtin_amdgcn_mfma_f32_16x16x32_bf16(qf[0], kf0, a, 0, 0, 0);
            a = __builtin_amdgcn_mfma_f32_16x16x32_bf16(qf[1], kf1, a, 0, 0, 0);
            if (!full2[ni]) {
                const int kj = kbase + ni * 16 + l15;
#pragma unroll
                for (int r = 0; r < 4; r++) {
                    const int qi = qabs0 + quad * 4 + r;
                    if (!((kj <= qi) && (qi - kj <= 256))) a[r] = -1e30f;
                }
            }
#pragma unroll
            for (int r = 0; r < 4; r++) {
                const float p = exp2f(a[r] - 17.312340f);   // 12*log2e
                li[r] += p;
                pw[(quad * 4 + r) * 72 + ni * 16 + l15] = f2bf(p);
            }
        }

#pragma unroll
        for (int ks = 0; ks < 2; ks++) {
            if (skip2[2 * ks] && skip2[2 * ks + 1]) continue;
            v8bf af = *(const v8bf*)&pw[l15 * 72 + ks * 32 + quad * 8];
#pragma unroll
            for (int nd = 0; nd < 4; nd++) {
                v8bf bv = *(const v8bf*)&VTs[(nd * 16 + l15) * 72 + ks * 32 + quad * 8];
                o[nd] = __builtin_amdgcn_mfma_f32_16x16x32_bf16(af, bv, o[nd], 0, 0, 0);
            }
        }
        BAR_LGKM();                                    // reads retired before next ds_write
    }
#undef LOADKV

#pragma unroll
    for (int off = 8; off >= 1; off >>= 1)
#pragma unroll
        for (int r = 0; r < 4; r++)
            li[r] += __shfl_xor(li[r], off, 64);
    float inv[4];
#pragma unroll
    for (int r = 0; r < 4; r++) inv[r] = 1.f / li[r];
#pragma unroll
    for (int nd = 0; nd < 4; nd++) {
        const int col = h * 64 + nd * 16 + l15;
#pragma unroll
        for (int r = 0; r < 4; r++) {
            const int row2 = tok0 + quad * 4 + r;
            yo[row2 * 1024 + col] = f2bf(o[nd][r] * inv[r]);
        }
    }
}

// ---------------------------------------------------------------------------
extern "C" void kernel_launch(void* const* d_in, const int* in_sizes, int n_in,
                              void* d_out, int out_size, void* d_ws, size_t ws_size,
                              hipStream_t stream)
{
    const float* x  = (const float*)d_in[0];
    const float* ve = (const float*)d_in[1];
    const float* cs = (const float*)d_in[2];
    const float* sn = (const float*)d_in[3];
    const float* Wq = (const float*)d_in[4];
    const float* Wk = (const float*)d_in[5];
    const float* Wv = (const float*)d_in[6];
    const float* Wo = (const float*)d_in[7];
    const float* Wg = (const float*)d_in[8];
    // d_in[9] = window_size (fixed 256, hard-coded)

    u16*   xb    = (u16*)d_ws;                 // 4096 x 1024
    u16*   wb    = xb  + 4096 * 1024;          // 1536 x 1024  [Wq;Wk;Wv]
    u16*   wob   = wb  + 1536 * 1024;          // 1024 x 1024  Wo
    u16*   qn    = wob + 1024 * 1024;          // 4096 x 1024
    u16*   kn    = qn  + 4096 * 1024;          // 4096 x 256
    u16*   vt    = kn  + 4096 * 256;           // [4][4][64][1024] transposed V
    u16*   ay    = vt  + 4096 * 256;           // 4096 x 1024 attention out
    float* gates = (float*)(ay + 4096 * 1024); // 4096 x 4

    convert6<<<dim3(512, 6), 256, 0, stream>>>(x, Wq, Wk, Wv, Wo, Wg, xb, wb, wob, gates);
    gemm_qkv<<<dim3(64, 12), 256, 0, stream>>>(xb, wb, cs, sn, gates, ve, qn, kn, vt);
    attn<<<dim3(16, 16, 4), 256, 0, stream>>>(qn, kn, vt, ay);
    gemm_out<<<dim3(64, 8), 256, 0, stream>>>(ay, wob, (float*)d_out, 1024);
}

// Round 10
// 144.183 us; speedup vs baseline: 1.1369x; 1.0436x over previous
//
#include <hip/hip_runtime.h>

typedef __bf16 v8bf __attribute__((ext_vector_type(8)));
typedef float v4f __attribute__((ext_vector_type(4)));
typedef unsigned int v4u __attribute__((ext_vector_type(4)));
typedef unsigned int v2u __attribute__((ext_vector_type(2)));
typedef unsigned short u16;

#define DEVI static __device__ __forceinline__

DEVI float bf2f(u16 u) {
    union { float f; unsigned int i; } c; c.i = ((unsigned int)u) << 16; return c.f;
}
DEVI u16 f2bf(float f) {
    union { __bf16 b; u16 u; } c; c.b = (__bf16)f;   // native HW cvt, RNE
    return c.u;
}

union Frag { v4u u; v8bf v; u16 h[8]; };

#define GLD16(gptr, lptr) __builtin_amdgcn_global_load_lds( \
    (const __attribute__((address_space(1))) void*)(gptr),  \
    (__attribute__((address_space(3))) void*)(lptr), 16, 0, 0)

// raw barrier + counted waits (no __syncthreads: it drains vmcnt(0) and
// kills in-flight prefetch).  "memory" clobber pins ordering.
#define BAR_VM6()  asm volatile("s_waitcnt vmcnt(6)\ns_barrier" ::: "memory")
#define BAR_VM0()  asm volatile("s_waitcnt vmcnt(0)\ns_barrier" ::: "memory")
#define BAR_LGKM() asm volatile("s_waitcnt lgkmcnt(0)\ns_barrier" ::: "memory")

// ---------------------------------------------------------------------------
// fp32 -> bf16 convert (x, Wq, Wk, Wv packed, Wo) + gate precompute (seg 5):
// gates[token*4+g] = 3*sigmoid(x[token,0:12] . Wg[g])
// ---------------------------------------------------------------------------
__global__ __launch_bounds__(256) void convert6(
    const float* __restrict__ x, const float* __restrict__ wq,
    const float* __restrict__ wk, const float* __restrict__ wv,
    const float* __restrict__ wo, const float* __restrict__ Wg,
    u16* __restrict__ xb, u16* __restrict__ wb, u16* __restrict__ wob,
    float* __restrict__ gates)
{
    if (blockIdx.y == 5) {
        const int stride = gridDim.x * 256;
        for (int i = blockIdx.x * 256 + threadIdx.x; i < 4096 * 4; i += stride) {
            const int token = i >> 2, g = i & 3;
            float dot = 0.f;
#pragma unroll
            for (int c = 0; c < 12; c++)
                dot += x[token * 1024 + c] * Wg[g * 12 + c];
            gates[i] = 3.f / (1.f + __expf(-dot));
        }
        return;
    }
    const float* src; u16* dst; int n;
    switch (blockIdx.y) {
        case 0: src = x;  dst = xb;               n = 4096 * 1024; break;
        case 1: src = wq; dst = wb;               n = 1024 * 1024; break;
        case 2: src = wk; dst = wb + 1024 * 1024; n = 256 * 1024;  break;
        case 3: src = wv; dst = wb + 1280 * 1024; n = 256 * 1024;  break;
        default: src = wo; dst = wob;             n = 1024 * 1024; break;
    }
    const int stride = gridDim.x * 256 * 4;
    for (int i = (blockIdx.x * 256 + threadIdx.x) * 4; i < n; i += stride) {
        const float4 f = *(const float4*)(src + i);
        v2u p;
        p[0] = (unsigned int)f2bf(f.x) | ((unsigned int)f2bf(f.y) << 16);
        p[1] = (unsigned int)f2bf(f.z) | ((unsigned int)f2bf(f.w) << 16);
        *(v2u*)(dst + i) = p;
    }
}

// ---------------------------------------------------------------------------
// QKV GEMM v3: 64x128 tile @ 768 blocks = 3/CU (r9 win) + LDS XOR-SWIZZLE.
// r8 counters: 4.7M bank-conflict cycles — [row][64]u16 tiles give bank ==
// f(quad) independent of row -> 16-way conflict on every ds_read_b128
// (~5.7x, m136), the cause of MfmaUtil 10.5%.  Fix per rule #21 (both-sides):
// GLD16 writes LDS linearly (HW: base+lane*16, can't swizzle), so the global
// SOURCE chunk is pre-permuted  chunk ^= row&7,  and fragment reads apply the
// same involution  physchunk = (ks*4+quad) ^ (l15&7).  All row offsets in
// staging (+32/+64/+96) and frags (wr/wc, mi*16, ni*16) are ==0 mod 8, so the
// XOR term is lane-invariant.  After: 16 lanes span 8 columns = 2-way = free.
// BK=64 dbuf, counted vmcnt(6).  Fused epilogue unchanged.
// ---------------------------------------------------------------------------
__global__ __launch_bounds__(256) void gemm_qkv(
    const u16* __restrict__ A, const u16* __restrict__ B,
    const float* __restrict__ cs, const float* __restrict__ sn,
    const float* __restrict__ gates, const float* __restrict__ ve,
    u16* __restrict__ qn, u16* __restrict__ kn, u16* __restrict__ vt)
{
    __shared__ __align__(16) u16 As[2][64 * 64];
    __shared__ __align__(16) u16 Bs[2][128 * 64];
    const int tid  = threadIdx.x;
    const int lane = tid & 63, l15 = lane & 15, quad = (lane >> 4) & 3;
    const int w    = tid >> 6;
    const int wr   = (w >> 1) * 32, wc = (w & 1) * 64;
    const int m0   = blockIdx.x * 64, n0 = blockIdx.y * 128;

    const int r0 = tid >> 3;                       // 0..31
    const int swc = ((tid & 7) ^ (r0 & 7)) * 8;    // pre-swizzled source chunk
    const u16* ag = A + (m0 + r0) * 1024 + swc;
    const u16* bg = B + (n0 + r0) * 1024 + swc;
    const int lo = r0 * 64 + (tid & 7) * 8;        // physical LDS dest (linear)
    const int rsw = l15 & 7;                       // read-side XOR term

    v4f acc[2][4];
    const v4f vzero = {0.f, 0.f, 0.f, 0.f};
#pragma unroll
    for (int i = 0; i < 2; i++)
#pragma unroll
        for (int j = 0; j < 4; j++) acc[i][j] = vzero;

#define QKV_STAGE(k0, buf) {                                        \
        const u16* a_ = ag + (k0);  const u16* b_ = bg + (k0);      \
        u16* al_ = &As[buf][lo];    u16* bl_ = &Bs[buf][lo];        \
        GLD16(a_,             al_);                                 \
        GLD16(a_ + 32 * 1024, al_ + 32 * 64);                       \
        GLD16(b_,             bl_);                                 \
        GLD16(b_ + 32 * 1024, bl_ + 32 * 64);                       \
        GLD16(b_ + 64 * 1024, bl_ + 64 * 64);                       \
        GLD16(b_ + 96 * 1024, bl_ + 96 * 64);                       \
    }

    QKV_STAGE(0, 0);
    for (int t = 0; t < 16; ++t) {
        if (t < 15) {
            QKV_STAGE((t + 1) * 64, (t + 1) & 1);
            BAR_VM6();              // tile t's 6 loads landed; t+1 in flight
        } else {
            BAR_VM0();
        }
        const u16* Asb = As[t & 1];
        const u16* Bsb = Bs[t & 1];
#pragma unroll
        for (int ks = 0; ks < 2; ks++) {
            const int pc = ((ks * 4 + quad) ^ rsw) * 8;   // swizzled read chunk
            v8bf af[2];
#pragma unroll
            for (int mi = 0; mi < 2; mi++)
                af[mi] = *(const v8bf*)&Asb[(wr + mi * 16 + l15) * 64 + pc];
#pragma unroll
            for (int ni = 0; ni < 4; ni++) {
                v8bf bv = *(const v8bf*)&Bsb[(wc + ni * 16 + l15) * 64 + pc];
#pragma unroll
                for (int mi = 0; mi < 2; mi++)
                    acc[mi][ni] = __builtin_amdgcn_mfma_f32_16x16x32_bf16(af[mi], bv, acc[mi][ni], 0, 0, 0);
            }
        }
        BAR_LGKM();                 // all reads of buf[t&1] retired
    }
#undef QKV_STAGE

    // ---- fused QKV epilogue ----
    const int hcol = n0 + wc;          // start col of this wave's head
    if (hcol < 1280) {                 // Q or K head: RoPE + RMS-norm
        const bool isQ = (hcol < 1024);
        u16* dst = isQ ? (qn + (hcol >> 6) * 64) : (kn + ((hcol - 1024) >> 6) * 64);
        const int dstride = isQ ? 1024 : 256;
#pragma unroll
        for (int mi = 0; mi < 2; mi++) {
#pragma unroll
            for (int r = 0; r < 4; r++) {
                const int row = m0 + wr + mi * 16 + quad * 4 + r;
                const int pos = row & 1023;
                const float c0_ = cs[pos * 32 + l15],      s0_ = sn[pos * 32 + l15];
                const float c1_ = cs[pos * 32 + 16 + l15], s1_ = sn[pos * 32 + 16 + l15];
                const float y0 = acc[mi][0][r] * c0_ + acc[mi][2][r] * s0_;
                const float y2 = acc[mi][2][r] * c0_ - acc[mi][0][r] * s0_;
                const float y1 = acc[mi][1][r] * c1_ + acc[mi][3][r] * s1_;
                const float y3 = acc[mi][3][r] * c1_ - acc[mi][1][r] * s1_;
                float ss = y0 * y0 + y1 * y1 + y2 * y2 + y3 * y3;
#pragma unroll
                for (int off = 8; off >= 1; off >>= 1)
                    ss += __shfl_xor(ss, off, 64);
                const float inv = rsqrtf(ss * (1.0f / 64.0f) + 1.1920929e-7f) * 1.2f;
                u16* d = dst + row * dstride;
                d[l15]      = f2bf(y0 * inv);
                d[16 + l15] = f2bf(y1 * inv);
                d[32 + l15] = f2bf(y2 * inv);
                d[48 + l15] = f2bf(y3 * inv);
            }
        }
    } else {                           // V head: + gate * ve, transposed store
        const int g = (hcol - 1280) >> 6;
#pragma unroll
        for (int mi = 0; mi < 2; mi++) {
            const int row0 = m0 + wr + mi * 16 + quad * 4;   // rows row0..row0+3
            const int b_ = row0 >> 10, t_ = row0 & 1023;     // same b for all 4 r
            float gate[4];
#pragma unroll
            for (int r = 0; r < 4; r++) gate[r] = gates[(row0 + r) * 4 + g];
#pragma unroll
            for (int ni = 0; ni < 4; ni++) {
                const int d = ni * 16 + l15;
                union { u16 h[4]; v2u u; } pk;
#pragma unroll
                for (int r = 0; r < 4; r++)
                    pk.h[r] = f2bf(acc[mi][ni][r] + gate[r] * ve[(row0 + r) * 256 + g * 64 + d]);
                // t_ is a multiple of 4 -> 8B-aligned store
                *(v2u*)&vt[((b_ * 4 + g) * 64 + d) * 1024 + t_] = pk.u;
            }
        }
    }
}

// ---------------------------------------------------------------------------
// Output projection GEMM: 64x128 BK=64 dbuf vmcnt(6), 512 blocks = 2/CU
// (r4 config) + the same LDS XOR-swizzle as gemm_qkv.  Plain fp32 store.
// ---------------------------------------------------------------------------
__global__ __launch_bounds__(256) void gemm_out(
    const u16* __restrict__ A, const u16* __restrict__ B,
    float* __restrict__ C, int N)
{
    __shared__ __align__(16) u16 As[2][64 * 64];
    __shared__ __align__(16) u16 Bs[2][128 * 64];
    const int tid  = threadIdx.x;
    const int lane = tid & 63, l15 = lane & 15, quad = (lane >> 4) & 3;
    const int w    = tid >> 6;
    const int wr   = (w >> 1) * 32, wc = (w & 1) * 64;
    const int m0   = blockIdx.x * 64, n0 = blockIdx.y * 128;

    const int r0 = tid >> 3;
    const int swc = ((tid & 7) ^ (r0 & 7)) * 8;    // pre-swizzled source chunk
    const u16* ag = A + (m0 + r0) * 1024 + swc;
    const u16* bg = B + (n0 + r0) * 1024 + swc;
    const int lo = r0 * 64 + (tid & 7) * 8;        // physical LDS dest (linear)
    const int rsw = l15 & 7;

    v4f acc[2][4];
    const v4f vzero = {0.f, 0.f, 0.f, 0.f};
#pragma unroll
    for (int i = 0; i < 2; i++)
#pragma unroll
        for (int j = 0; j < 4; j++) acc[i][j] = vzero;

#define OUT_STAGE(k0, buf) {                                        \
        const u16* a_ = ag + (k0);  const u16* b_ = bg + (k0);      \
        u16* al_ = &As[buf][lo];    u16* bl_ = &Bs[buf][lo];        \
        GLD16(a_,             al_);                                 \
        GLD16(a_ + 32 * 1024, al_ + 32 * 64);                       \
        GLD16(b_,             bl_);                                 \
        GLD16(b_ + 32 * 1024, bl_ + 32 * 64);                       \
        GLD16(b_ + 64 * 1024, bl_ + 64 * 64);                       \
        GLD16(b_ + 96 * 1024, bl_ + 96 * 64);                       \
    }

    OUT_STAGE(0, 0);
    for (int t = 0; t < 16; ++t) {
        if (t < 15) {
            OUT_STAGE((t + 1) * 64, (t + 1) & 1);
            BAR_VM6();
        } else {
            BAR_VM0();
        }
        const u16* Asb = As[t & 1];
        const u16* Bsb = Bs[t & 1];
#pragma unroll
        for (int ks = 0; ks < 2; ks++) {
            const int pc = ((ks * 4 + quad) ^ rsw) * 8;
            v8bf af[2];
#pragma unroll
            for (int mi = 0; mi < 2; mi++)
                af[mi] = *(const v8bf*)&Asb[(wr + mi * 16 + l15) * 64 + pc];
#pragma unroll
            for (int ni = 0; ni < 4; ni++) {
                v8bf bv = *(const v8bf*)&Bsb[(wc + ni * 16 + l15) * 64 + pc];
#pragma unroll
                for (int mi = 0; mi < 2; mi++)
                    acc[mi][ni] = __builtin_amdgcn_mfma_f32_16x16x32_bf16(af[mi], bv, acc[mi][ni], 0, 0, 0);
            }
        }
        BAR_LGKM();
    }
#undef OUT_STAGE

#pragma unroll
    for (int mi = 0; mi < 2; mi++) {
        const int row = m0 + wr + mi * 16 + quad * 4;
#pragma unroll
        for (int ni = 0; ni < 4; ni++) {
            const int col = n0 + wc + ni * 16 + l15;
#pragma unroll
            for (int r = 0; r < 4; r++)
                C[(row + r) * N + col] = acc[mi][ni][r];
        }
    }
}

// ---------------------------------------------------------------------------
// Sliding-window flash attention v8 (r4/r9 known-good).  QBLK=64 + T14
// async-stage split; K/V tile t+1 prefetched into registers before
// compute(t).  Single-buffered LDS (25 KB) -> 4 blocks/CU.  72-padding
// already de-conflicts (144 B row stride -> 4-bank row offset).
// Fixed-max softmax with base-2 exp: Q pre-scaled by 0.125*log2(e);
// p = exp2(a - 12*log2e) is a single v_exp_f32.
// ---------------------------------------------------------------------------
__global__ __launch_bounds__(256) void attn(
    const u16* __restrict__ qn, const u16* __restrict__ kn,
    const u16* __restrict__ vt, u16* __restrict__ yo)
{
    __shared__ __align__(16) u16 Ks[64 * 72];
    __shared__ __align__(16) u16 VTs[64 * 72];
    __shared__ __align__(16) u16 Ps[4][16 * 72];
    const int tid  = threadIdx.x;
    const int w    = tid >> 6, lane = tid & 63, l15 = lane & 15, quad = (lane >> 4) & 3;
    const int qb   = blockIdx.x, h = blockIdx.y, b = blockIdx.z;
    const int g    = h >> 2;
    const int qbase = qb * 64;
    const int qabs0 = qbase + w * 16;     // this wave's 16 q-rows
    const int tok0  = b * 1024 + qabs0;
    u16* pw = Ps[w];

    v8bf qf[2];
#pragma unroll
    for (int ks = 0; ks < 2; ks++) {
        Frag f;
        f.u = *(const v4u*)&qn[(tok0 + l15) * 1024 + h * 64 + ks * 32 + quad * 8];
#pragma unroll
        for (int j = 0; j < 8; j++) f.h[j] = f2bf(0.18033688f * bf2f(f.h[j]));  // 0.125*log2e
        qf[ks] = f.v;
    }

    v4f o[4];
    float li[4];
    const v4f vzero = {0.f, 0.f, 0.f, 0.f};
#pragma unroll
    for (int nd = 0; nd < 4; nd++) o[nd] = vzero;
#pragma unroll
    for (int r = 0; r < 4; r++) li[r] = 0.f;

    const int row = tid >> 2, ch = (tid & 3) * 16;
    const int kstart = (qbase >= 256) ? qbase - 256 : 0;
    const int kend   = qbase;          // tile [kend, kend+63] covers q-row qbase+63

    // prefetch registers (named, compile-time indexed — rule #20)
    v4u ka, kb, va, vb;
#define LOADKV(kb_)  {                                                        \
        const int goff_ = (b * 1024 + (kb_) + row) * 256 + g * 64 + ch;       \
        ka = *(const v4u*)&kn[goff_];                                         \
        kb = *(const v4u*)&kn[goff_ + 8];                                     \
        const u16* vs_ = vt + ((b * 4 + g) * 64 + row) * 1024 + (kb_) + ch;   \
        va = *(const v4u*)vs_;                                                \
        vb = *(const v4u*)(vs_ + 8);                                          \
    }

    LOADKV(kstart);
    for (int kbase = kstart; kbase <= kend; kbase += 64) {
        // write current tile (compiler inserts the vmcnt wait on ka..vb)
        *(v4u*)&Ks[row * 72 + ch]      = ka;
        *(v4u*)&Ks[row * 72 + ch + 8]  = kb;
        *(v4u*)&VTs[row * 72 + ch]     = va;
        *(v4u*)&VTs[row * 72 + ch + 8] = vb;
        if (kbase + 64 <= kend) LOADKV(kbase + 64);   // prefetch next (uniform branch)
        BAR_LGKM();                                    // LDS writes visible

        bool skip2[4], full2[4];
#pragma unroll
        for (int ni = 0; ni < 4; ni++) {
            const int left = kbase + ni * 16;
            skip2[ni] = (left > qabs0 + 15) || (qabs0 - (left + 15) > 256);
            full2[ni] = ((left + 15) <= qabs0) && ((qabs0 + 15 - left) <= 256);
        }

#pragma unroll
        for (int ni = 0; ni < 4; ni++) {
            if (skip2[ni]) {
#pragma unroll
                for (int r = 0; r < 4; r++)
                    pw[(quad * 4 + r) * 72 + ni * 16 + l15] = 0;
                continue;
            }
            v8bf kf0 = *(const v8bf*)&Ks[(ni * 16 + l15) * 72 + quad * 8];
            v8bf kf1 = *(const v8bf*)&Ks[(ni * 16 + l15) * 72 + 32 + quad * 8];
            v4f a = vzero;
            a = __builtin_amdgcn_mfma_f32_16x16x32_bf16(qf[0], kf0, a, 0, 0, 0);
            a = __builtin_amdgcn_mfma_f32_16x16x32_bf16(qf[1], kf1, a, 0, 0, 0);
            if (!full2[ni]) {
                const int kj = kbase + ni * 16 + l15;
#pragma unroll
                for (int r = 0; r < 4; r++) {
                    const int qi = qabs0 + quad * 4 + r;
                    if (!((kj <= qi) && (qi - kj <= 256))) a[r] = -1e30f;
                }
            }
#pragma unroll
            for (int r = 0; r < 4; r++) {
                const float p = exp2f(a[r] - 17.312340f);   // 12*log2e
                li[r] += p;
                pw[(quad * 4 + r) * 72 + ni * 16 + l15] = f2bf(p);
            }
        }

#pragma unroll
        for (int ks = 0; ks < 2; ks++) {
            if (skip2[2 * ks] && skip2[2 * ks + 1]) continue;
            v8bf af = *(const v8bf*)&pw[l15 * 72 + ks * 32 + quad * 8];
#pragma unroll
            for (int nd = 0; nd < 4; nd++) {
                v8bf bv = *(const v8bf*)&VTs[(nd * 16 + l15) * 72 + ks * 32 + quad * 8];
                o[nd] = __builtin_amdgcn_mfma_f32_16x16x32_bf16(af, bv, o[nd], 0, 0, 0);
            }
        }
        BAR_LGKM();                                    // reads retired before next ds_write
    }
#undef LOADKV

#pragma unroll
    for (int off = 8; off >= 1; off >>= 1)
#pragma unroll
        for (int r = 0; r < 4; r++)
            li[r] += __shfl_xor(li[r], off, 64);
    float inv[4];
#pragma unroll
    for (int r = 0; r < 4; r++) inv[r] = 1.f / li[r];
#pragma unroll
    for (int nd = 0; nd < 4; nd++) {
        const int col = h * 64 + nd * 16 + l15;
#pragma unroll
        for (int r = 0; r < 4; r++) {
            const int row2 = tok0 + quad * 4 + r;
            yo[row2 * 1024 + col] = f2bf(o[nd][r] * inv[r]);
        }
    }
}

// ---------------------------------------------------------------------------
extern "C" void kernel_launch(void* const* d_in, const int* in_sizes, int n_in,
                              void* d_out, int out_size, void* d_ws, size_t ws_size,
                              hipStream_t stream)
{
    const float* x  = (const float*)d_in[0];
    const float* ve = (const float*)d_in[1];
    const float* cs = (const float*)d_in[2];
    const float* sn = (const float*)d_in[3];
    const float* Wq = (const float*)d_in[4];
    const float* Wk = (const float*)d_in[5];
    const float* Wv = (const float*)d_in[6];
    const float* Wo = (const float*)d_in[7];
    const float* Wg = (const float*)d_in[8];
    // d_in[9] = window_size (fixed 256, hard-coded)

    u16*   xb    = (u16*)d_ws;                 // 4096 x 1024
    u16*   wb    = xb  + 4096 * 1024;          // 1536 x 1024  [Wq;Wk;Wv]
    u16*   wob   = wb  + 1536 * 1024;          // 1024 x 1024  Wo
    u16*   qn    = wob + 1024 * 1024;          // 4096 x 1024
    u16*   kn    = qn  + 4096 * 1024;          // 4096 x 256
    u16*   vt    = kn  + 4096 * 256;           // [4][4][64][1024] transposed V
    u16*   ay    = vt  + 4096 * 256;           // 4096 x 1024 attention out
    float* gates = (float*)(ay + 4096 * 1024); // 4096 x 4

    convert6<<<dim3(512, 6), 256, 0, stream>>>(x, Wq, Wk, Wv, Wo, Wg, xb, wb, wob, gates);
    gemm_qkv<<<dim3(64, 12), 256, 0, stream>>>(xb, wb, cs, sn, gates, ve, qn, kn, vt);
    attn<<<dim3(16, 16, 4), 256, 0, stream>>>(qn, kn, vt, ay);
    gemm_out<<<dim3(64, 8), 256, 0, stream>>>(ay, wob, (float*)d_out, 1024);
}

// Round 11
// 140.507 us; speedup vs baseline: 1.1667x; 1.0262x over previous
//
#include <hip/hip_runtime.h>

typedef __bf16 v8bf __attribute__((ext_vector_type(8)));
typedef float v4f __attribute__((ext_vector_type(4)));
typedef unsigned int v4u __attribute__((ext_vector_type(4)));
typedef unsigned int v2u __attribute__((ext_vector_type(2)));
typedef unsigned short u16;

#define DEVI static __device__ __forceinline__

DEVI float bf2f(u16 u) {
    union { float f; unsigned int i; } c; c.i = ((unsigned int)u) << 16; return c.f;
}
DEVI u16 f2bf(float f) {
    union { __bf16 b; u16 u; } c; c.b = (__bf16)f;   // native HW cvt, RNE
    return c.u;
}

union Frag { v4u u; v8bf v; u16 h[8]; };

#define GLD16(gptr, lptr) __builtin_amdgcn_global_load_lds( \
    (const __attribute__((address_space(1))) void*)(gptr),  \
    (__attribute__((address_space(3))) void*)(lptr), 16, 0, 0)

// raw barrier + counted waits (no __syncthreads: it drains vmcnt(0) and
// kills in-flight prefetch).  "memory" clobber pins ordering.
#define BAR_VM6()  asm volatile("s_waitcnt vmcnt(6)\ns_barrier" ::: "memory")
#define BAR_VM4()  asm volatile("s_waitcnt vmcnt(4)\ns_barrier" ::: "memory")
#define BAR_VM0()  asm volatile("s_waitcnt vmcnt(0)\ns_barrier" ::: "memory")
#define BAR_LGKM() asm volatile("s_waitcnt lgkmcnt(0)\ns_barrier" ::: "memory")

// ---------------------------------------------------------------------------
// fp32 -> bf16 convert (x, Wq, Wk, Wv packed, Wo) + gate precompute (seg 5):
// gates[token*4+g] = 3*sigmoid(x[token,0:12] . Wg[g])
// ---------------------------------------------------------------------------
__global__ __launch_bounds__(256) void convert6(
    const float* __restrict__ x, const float* __restrict__ wq,
    const float* __restrict__ wk, const float* __restrict__ wv,
    const float* __restrict__ wo, const float* __restrict__ Wg,
    u16* __restrict__ xb, u16* __restrict__ wb, u16* __restrict__ wob,
    float* __restrict__ gates)
{
    if (blockIdx.y == 5) {
        const int stride = gridDim.x * 256;
        for (int i = blockIdx.x * 256 + threadIdx.x; i < 4096 * 4; i += stride) {
            const int token = i >> 2, g = i & 3;
            float dot = 0.f;
#pragma unroll
            for (int c = 0; c < 12; c++)
                dot += x[token * 1024 + c] * Wg[g * 12 + c];
            gates[i] = 3.f / (1.f + __expf(-dot));
        }
        return;
    }
    const float* src; u16* dst; int n;
    switch (blockIdx.y) {
        case 0: src = x;  dst = xb;               n = 4096 * 1024; break;
        case 1: src = wq; dst = wb;               n = 1024 * 1024; break;
        case 2: src = wk; dst = wb + 1024 * 1024; n = 256 * 1024;  break;
        case 3: src = wv; dst = wb + 1280 * 1024; n = 256 * 1024;  break;
        default: src = wo; dst = wob;             n = 1024 * 1024; break;
    }
    const int stride = gridDim.x * 256 * 4;
    for (int i = (blockIdx.x * 256 + threadIdx.x) * 4; i < n; i += stride) {
        const float4 f = *(const float4*)(src + i);
        v2u p;
        p[0] = (unsigned int)f2bf(f.x) | ((unsigned int)f2bf(f.y) << 16);
        p[1] = (unsigned int)f2bf(f.z) | ((unsigned int)f2bf(f.w) << 16);
        *(v2u*)(dst + i) = p;
    }
}

// ---------------------------------------------------------------------------
// QKV GEMM v3 (r10 best): 64x128 tile @ 768 blocks = 3/CU + both-sides LDS
// XOR-swizzle (source chunk ^= row&7; read chunk = (ks*4+quad)^(l15&7)).
// BK=64 dbuf, counted vmcnt(6).  Fused epilogue — wave owns 32 tokens x ONE
// full 64-d head (RoPE pairing requires 64-col waves):
//   Q: RoPE + RMS-norm *1.2 -> qn   K: same -> kn
//   V: acc + gates*ve, written TRANSPOSED straight to vt
// ---------------------------------------------------------------------------
__global__ __launch_bounds__(256) void gemm_qkv(
    const u16* __restrict__ A, const u16* __restrict__ B,
    const float* __restrict__ cs, const float* __restrict__ sn,
    const float* __restrict__ gates, const float* __restrict__ ve,
    u16* __restrict__ qn, u16* __restrict__ kn, u16* __restrict__ vt)
{
    __shared__ __align__(16) u16 As[2][64 * 64];
    __shared__ __align__(16) u16 Bs[2][128 * 64];
    const int tid  = threadIdx.x;
    const int lane = tid & 63, l15 = lane & 15, quad = (lane >> 4) & 3;
    const int w    = tid >> 6;
    const int wr   = (w >> 1) * 32, wc = (w & 1) * 64;
    const int m0   = blockIdx.x * 64, n0 = blockIdx.y * 128;

    const int r0 = tid >> 3;                       // 0..31
    const int swc = ((tid & 7) ^ (r0 & 7)) * 8;    // pre-swizzled source chunk
    const u16* ag = A + (m0 + r0) * 1024 + swc;
    const u16* bg = B + (n0 + r0) * 1024 + swc;
    const int lo = r0 * 64 + (tid & 7) * 8;        // physical LDS dest (linear)
    const int rsw = l15 & 7;                       // read-side XOR term

    v4f acc[2][4];
    const v4f vzero = {0.f, 0.f, 0.f, 0.f};
#pragma unroll
    for (int i = 0; i < 2; i++)
#pragma unroll
        for (int j = 0; j < 4; j++) acc[i][j] = vzero;

#define QKV_STAGE(k0, buf) {                                        \
        const u16* a_ = ag + (k0);  const u16* b_ = bg + (k0);      \
        u16* al_ = &As[buf][lo];    u16* bl_ = &Bs[buf][lo];        \
        GLD16(a_,             al_);                                 \
        GLD16(a_ + 32 * 1024, al_ + 32 * 64);                       \
        GLD16(b_,             bl_);                                 \
        GLD16(b_ + 32 * 1024, bl_ + 32 * 64);                       \
        GLD16(b_ + 64 * 1024, bl_ + 64 * 64);                       \
        GLD16(b_ + 96 * 1024, bl_ + 96 * 64);                       \
    }

    QKV_STAGE(0, 0);
    for (int t = 0; t < 16; ++t) {
        if (t < 15) {
            QKV_STAGE((t + 1) * 64, (t + 1) & 1);
            BAR_VM6();              // tile t's 6 loads landed; t+1 in flight
        } else {
            BAR_VM0();
        }
        const u16* Asb = As[t & 1];
        const u16* Bsb = Bs[t & 1];
#pragma unroll
        for (int ks = 0; ks < 2; ks++) {
            const int pc = ((ks * 4 + quad) ^ rsw) * 8;   // swizzled read chunk
            v8bf af[2];
#pragma unroll
            for (int mi = 0; mi < 2; mi++)
                af[mi] = *(const v8bf*)&Asb[(wr + mi * 16 + l15) * 64 + pc];
#pragma unroll
            for (int ni = 0; ni < 4; ni++) {
                v8bf bv = *(const v8bf*)&Bsb[(wc + ni * 16 + l15) * 64 + pc];
#pragma unroll
                for (int mi = 0; mi < 2; mi++)
                    acc[mi][ni] = __builtin_amdgcn_mfma_f32_16x16x32_bf16(af[mi], bv, acc[mi][ni], 0, 0, 0);
            }
        }
        BAR_LGKM();                 // all reads of buf[t&1] retired
    }
#undef QKV_STAGE

    // ---- fused QKV epilogue ----
    const int hcol = n0 + wc;          // start col of this wave's head
    if (hcol < 1280) {                 // Q or K head: RoPE + RMS-norm
        const bool isQ = (hcol < 1024);
        u16* dst = isQ ? (qn + (hcol >> 6) * 64) : (kn + ((hcol - 1024) >> 6) * 64);
        const int dstride = isQ ? 1024 : 256;
#pragma unroll
        for (int mi = 0; mi < 2; mi++) {
#pragma unroll
            for (int r = 0; r < 4; r++) {
                const int row = m0 + wr + mi * 16 + quad * 4 + r;
                const int pos = row & 1023;
                const float c0_ = cs[pos * 32 + l15],      s0_ = sn[pos * 32 + l15];
                const float c1_ = cs[pos * 32 + 16 + l15], s1_ = sn[pos * 32 + 16 + l15];
                const float y0 = acc[mi][0][r] * c0_ + acc[mi][2][r] * s0_;
                const float y2 = acc[mi][2][r] * c0_ - acc[mi][0][r] * s0_;
                const float y1 = acc[mi][1][r] * c1_ + acc[mi][3][r] * s1_;
                const float y3 = acc[mi][3][r] * c1_ - acc[mi][1][r] * s1_;
                float ss = y0 * y0 + y1 * y1 + y2 * y2 + y3 * y3;
#pragma unroll
                for (int off = 8; off >= 1; off >>= 1)
                    ss += __shfl_xor(ss, off, 64);
                const float inv = rsqrtf(ss * (1.0f / 64.0f) + 1.1920929e-7f) * 1.2f;
                u16* d = dst + row * dstride;
                d[l15]      = f2bf(y0 * inv);
                d[16 + l15] = f2bf(y1 * inv);
                d[32 + l15] = f2bf(y2 * inv);
                d[48 + l15] = f2bf(y3 * inv);
            }
        }
    } else {                           // V head: + gate * ve, transposed store
        const int g = (hcol - 1280) >> 6;
#pragma unroll
        for (int mi = 0; mi < 2; mi++) {
            const int row0 = m0 + wr + mi * 16 + quad * 4;   // rows row0..row0+3
            const int b_ = row0 >> 10, t_ = row0 & 1023;     // same b for all 4 r
            float gate[4];
#pragma unroll
            for (int r = 0; r < 4; r++) gate[r] = gates[(row0 + r) * 4 + g];
#pragma unroll
            for (int ni = 0; ni < 4; ni++) {
                const int d = ni * 16 + l15;
                union { u16 h[4]; v2u u; } pk;
#pragma unroll
                for (int r = 0; r < 4; r++)
                    pk.h[r] = f2bf(acc[mi][ni][r] + gate[r] * ve[(row0 + r) * 256 + g * 64 + d]);
                // t_ is a multiple of 4 -> 8B-aligned store
                *(v2u*)&vt[((b_ * 4 + g) * 64 + d) * 1024 + t_] = pk.u;
            }
        }
    }
}

// ---------------------------------------------------------------------------
// Output projection GEMM v3: 64x64 tile -> grid (64,16) = 1024 blocks =
// 4 blocks/CU (was 64x128 @ 512 = 2/CU).  Same occupancy lever that won
// r8->r9 on qkv: staging intensity worsens (4 GLD16 : 32 MFMA vs 6 : 64)
// but blocks/CU doubles — session evidence says TLP dominates at this size.
// 4 waves x 32x32 output (2x2 frags), BK=64 dbuf, counted vmcnt(4),
// both-sides XOR swizzle.  Plain fp32 store.
// ---------------------------------------------------------------------------
__global__ __launch_bounds__(256) void gemm_out(
    const u16* __restrict__ A, const u16* __restrict__ B,
    float* __restrict__ C, int N)
{
    __shared__ __align__(16) u16 As[2][64 * 64];
    __shared__ __align__(16) u16 Bs[2][64 * 64];
    const int tid  = threadIdx.x;
    const int lane = tid & 63, l15 = lane & 15, quad = (lane >> 4) & 3;
    const int w    = tid >> 6;
    const int wr   = (w >> 1) * 32, wc = (w & 1) * 32;
    const int m0   = blockIdx.x * 64, n0 = blockIdx.y * 64;

    const int r0 = tid >> 3;
    const int swc = ((tid & 7) ^ (r0 & 7)) * 8;    // pre-swizzled source chunk
    const u16* ag = A + (m0 + r0) * 1024 + swc;
    const u16* bg = B + (n0 + r0) * 1024 + swc;
    const int lo = r0 * 64 + (tid & 7) * 8;        // physical LDS dest (linear)
    const int rsw = l15 & 7;

    v4f acc[2][2];
    const v4f vzero = {0.f, 0.f, 0.f, 0.f};
#pragma unroll
    for (int i = 0; i < 2; i++)
#pragma unroll
        for (int j = 0; j < 2; j++) acc[i][j] = vzero;

#define OUT_STAGE(k0, buf) {                                        \
        const u16* a_ = ag + (k0);  const u16* b_ = bg + (k0);      \
        u16* al_ = &As[buf][lo];    u16* bl_ = &Bs[buf][lo];        \
        GLD16(a_,             al_);                                 \
        GLD16(a_ + 32 * 1024, al_ + 32 * 64);                       \
        GLD16(b_,             bl_);                                 \
        GLD16(b_ + 32 * 1024, bl_ + 32 * 64);                       \
    }

    OUT_STAGE(0, 0);
    for (int t = 0; t < 16; ++t) {
        if (t < 15) {
            OUT_STAGE((t + 1) * 64, (t + 1) & 1);
            BAR_VM4();              // tile t's 4 loads landed; t+1 in flight
        } else {
            BAR_VM0();
        }
        const u16* Asb = As[t & 1];
        const u16* Bsb = Bs[t & 1];
#pragma unroll
        for (int ks = 0; ks < 2; ks++) {
            const int pc = ((ks * 4 + quad) ^ rsw) * 8;
            v8bf af[2], bv[2];
#pragma unroll
            for (int mi = 0; mi < 2; mi++)
                af[mi] = *(const v8bf*)&Asb[(wr + mi * 16 + l15) * 64 + pc];
#pragma unroll
            for (int ni = 0; ni < 2; ni++)
                bv[ni] = *(const v8bf*)&Bsb[(wc + ni * 16 + l15) * 64 + pc];
#pragma unroll
            for (int ni = 0; ni < 2; ni++)
#pragma unroll
                for (int mi = 0; mi < 2; mi++)
                    acc[mi][ni] = __builtin_amdgcn_mfma_f32_16x16x32_bf16(af[mi], bv[ni], acc[mi][ni], 0, 0, 0);
        }
        BAR_LGKM();
    }
#undef OUT_STAGE

#pragma unroll
    for (int mi = 0; mi < 2; mi++) {
        const int row = m0 + wr + mi * 16 + quad * 4;
#pragma unroll
        for (int ni = 0; ni < 2; ni++) {
            const int col = n0 + wc + ni * 16 + l15;
#pragma unroll
            for (int r = 0; r < 4; r++)
                C[(row + r) * N + col] = acc[mi][ni][r];
        }
    }
}

// ---------------------------------------------------------------------------
// Sliding-window flash attention v8 (r4/r9/r10 known-good).  QBLK=64 + T14
// async-stage split; K/V tile t+1 prefetched into registers before
// compute(t).  Single-buffered LDS (27.6 KB) -> 4 blocks/CU.  72-padding
// already de-conflicts (144 B row stride -> 4-bank row offset).
// Fixed-max softmax with base-2 exp: Q pre-scaled by 0.125*log2(e);
// p = exp2(a - 12*log2e) is a single v_exp_f32.
// ---------------------------------------------------------------------------
__global__ __launch_bounds__(256) void attn(
    const u16* __restrict__ qn, const u16* __restrict__ kn,
    const u16* __restrict__ vt, u16* __restrict__ yo)
{
    __shared__ __align__(16) u16 Ks[64 * 72];
    __shared__ __align__(16) u16 VTs[64 * 72];
    __shared__ __align__(16) u16 Ps[4][16 * 72];
    const int tid  = threadIdx.x;
    const int w    = tid >> 6, lane = tid & 63, l15 = lane & 15, quad = (lane >> 4) & 3;
    const int qb   = blockIdx.x, h = blockIdx.y, b = blockIdx.z;
    const int g    = h >> 2;
    const int qbase = qb * 64;
    const int qabs0 = qbase + w * 16;     // this wave's 16 q-rows
    const int tok0  = b * 1024 + qabs0;
    u16* pw = Ps[w];

    v8bf qf[2];
#pragma unroll
    for (int ks = 0; ks < 2; ks++) {
        Frag f;
        f.u = *(const v4u*)&qn[(tok0 + l15) * 1024 + h * 64 + ks * 32 + quad * 8];
#pragma unroll
        for (int j = 0; j < 8; j++) f.h[j] = f2bf(0.18033688f * bf2f(f.h[j]));  // 0.125*log2e
        qf[ks] = f.v;
    }

    v4f o[4];
    float li[4];
    const v4f vzero = {0.f, 0.f, 0.f, 0.f};
#pragma unroll
    for (int nd = 0; nd < 4; nd++) o[nd] = vzero;
#pragma unroll
    for (int r = 0; r < 4; r++) li[r] = 0.f;

    const int row = tid >> 2, ch = (tid & 3) * 16;
    const int kstart = (qbase >= 256) ? qbase - 256 : 0;
    const int kend   = qbase;          // tile [kend, kend+63] covers q-row qbase+63

    // prefetch registers (named, compile-time indexed — rule #20)
    v4u ka, kb, va, vb;
#define LOADKV(kb_)  {                                                        \
        const int goff_ = (b * 1024 + (kb_) + row) * 256 + g * 64 + ch;       \
        ka = *(const v4u*)&kn[goff_];                                         \
        kb = *(const v4u*)&kn[goff_ + 8];                                     \
        const u16* vs_ = vt + ((b * 4 + g) * 64 + row) * 1024 + (kb_) + ch;   \
        va = *(const v4u*)vs_;                                                \
        vb = *(const v4u*)(vs_ + 8);                                          \
    }

    LOADKV(kstart);
    for (int kbase = kstart; kbase <= kend; kbase += 64) {
        // write current tile (compiler inserts the vmcnt wait on ka..vb)
        *(v4u*)&Ks[row * 72 + ch]      = ka;
        *(v4u*)&Ks[row * 72 + ch + 8]  = kb;
        *(v4u*)&VTs[row * 72 + ch]     = va;
        *(v4u*)&VTs[row * 72 + ch + 8] = vb;
        if (kbase + 64 <= kend) LOADKV(kbase + 64);   // prefetch next (uniform branch)
        BAR_LGKM();                                    // LDS writes visible

        bool skip2[4], full2[4];
#pragma unroll
        for (int ni = 0; ni < 4; ni++) {
            const int left = kbase + ni * 16;
            skip2[ni] = (left > qabs0 + 15) || (qabs0 - (left + 15) > 256);
            full2[ni] = ((left + 15) <= qabs0) && ((qabs0 + 15 - left) <= 256);
        }

#pragma unroll
        for (int ni = 0; ni < 4; ni++) {
            if (skip2[ni]) {
#pragma unroll
                for (int r = 0; r < 4; r++)
                    pw[(quad * 4 + r) * 72 + ni * 16 + l15] = 0;
                continue;
            }
            v8bf kf0 = *(const v8bf*)&Ks[(ni * 16 + l15) * 72 + quad * 8];
            v8bf kf1 = *(const v8bf*)&Ks[(ni * 16 + l15) * 72 + 32 + quad * 8];
            v4f a = vzero;
            a = __builtin_amdgcn_mfma_f32_16x16x32_bf16(qf[0], kf0, a, 0, 0, 0);
            a = __builtin_amdgcn_mfma_f32_16x16x32_bf16(qf[1], kf1, a, 0, 0, 0);
            if (!full2[ni]) {
                const int kj = kbase + ni * 16 + l15;
#pragma unroll
                for (int r = 0; r < 4; r++) {
                    const int qi = qabs0 + quad * 4 + r;
                    if (!((kj <= qi) && (qi - kj <= 256))) a[r] = -1e30f;
                }
            }
#pragma unroll
            for (int r = 0; r < 4; r++) {
                const float p = exp2f(a[r] - 17.312340f);   // 12*log2e
                li[r] += p;
                pw[(quad * 4 + r) * 72 + ni * 16 + l15] = f2bf(p);
            }
        }

#pragma unroll
        for (int ks = 0; ks < 2; ks++) {
            if (skip2[2 * ks] && skip2[2 * ks + 1]) continue;
            v8bf af = *(const v8bf*)&pw[l15 * 72 + ks * 32 + quad * 8];
#pragma unroll
            for (int nd = 0; nd < 4; nd++) {
                v8bf bv = *(const v8bf*)&VTs[(nd * 16 + l15) * 72 + ks * 32 + quad * 8];
                o[nd] = __builtin_amdgcn_mfma_f32_16x16x32_bf16(af, bv, o[nd], 0, 0, 0);
            }
        }
        BAR_LGKM();                                    // reads retired before next ds_write
    }
#undef LOADKV

#pragma unroll
    for (int off = 8; off >= 1; off >>= 1)
#pragma unroll
        for (int r = 0; r < 4; r++)
            li[r] += __shfl_xor(li[r], off, 64);
    float inv[4];
#pragma unroll
    for (int r = 0; r < 4; r++) inv[r] = 1.f / li[r];
#pragma unroll
    for (int nd = 0; nd < 4; nd++) {
        const int col = h * 64 + nd * 16 + l15;
#pragma unroll
        for (int r = 0; r < 4; r++) {
            const int row2 = tok0 + quad * 4 + r;
            yo[row2 * 1024 + col] = f2bf(o[nd][r] * inv[r]);
        }
    }
}

// ---------------------------------------------------------------------------
extern "C" void kernel_launch(void* const* d_in, const int* in_sizes, int n_in,
                              void* d_out, int out_size, void* d_ws, size_t ws_size,
                              hipStream_t stream)
{
    const float* x  = (const float*)d_in[0];
    const float* ve = (const float*)d_in[1];
    const float* cs = (const float*)d_in[2];
    const float* sn = (const float*)d_in[3];
    const float* Wq = (const float*)d_in[4];
    const float* Wk = (const float*)d_in[5];
    const float* Wv = (const float*)d_in[6];
    const float* Wo = (const float*)d_in[7];
    const float* Wg = (const float*)d_in[8];
    // d_in[9] = window_size (fixed 256, hard-coded)

    u16*   xb    = (u16*)d_ws;                 // 4096 x 1024
    u16*   wb    = xb  + 4096 * 1024;          // 1536 x 1024  [Wq;Wk;Wv]
    u16*   wob   = wb  + 1536 * 1024;          // 1024 x 1024  Wo
    u16*   qn    = wob + 1024 * 1024;          // 4096 x 1024
    u16*   kn    = qn  + 4096 * 1024;          // 4096 x 256
    u16*   vt    = kn  + 4096 * 256;           // [4][4][64][1024] transposed V
    u16*   ay    = vt  + 4096 * 256;           // 4096 x 1024 attention out
    float* gates = (float*)(ay + 4096 * 1024); // 4096 x 4

    convert6<<<dim3(512, 6), 256, 0, stream>>>(x, Wq, Wk, Wv, Wo, Wg, xb, wb, wob, gates);
    gemm_qkv<<<dim3(64, 12), 256, 0, stream>>>(xb, wb, cs, sn, gates, ve, qn, kn, vt);
    attn<<<dim3(16, 16, 4), 256, 0, stream>>>(qn, kn, vt, ay);
    gemm_out<<<dim3(64, 16), 256, 0, stream>>>(ay, wob, (float*)d_out, 1024);
}